// Round 1
// 3160.981 us; speedup vs baseline: 1.3388x; 1.3388x over previous
//
#include <hip/hip_runtime.h>

// S=1024 seq, B=32 batch, H=512 hid, E=512 emb, A=256 att — ALL f32 per reference
#define Sn 1024
#define Bn 32
#define Hn 512
#define En 512
#define An 256

// ---------------- projection: out[b][s][a] = scale*(X[s*B+b][:] . W[a][:] + bias[a])
// X: [S*B][512] f32, W: [256][512] f32. 16 rows/block, 256 threads (col=a=tid).
__global__ __launch_bounds__(256) void proj_kernel(const float* __restrict__ X,
                                                   const float* __restrict__ W,
                                                   const float* __restrict__ bias,
                                                   float* __restrict__ outp){
  __shared__ float xs[16][512];
  int tid = threadIdx.x;
  long r0 = (long)blockIdx.x * 16;
  const float4* src = (const float4*)(X + r0 * 512);   // 16 rows = 2048 float4
  #pragma unroll
  for (int i = 0; i < 8; i++){
    int idx = i * 256 + tid;
    float4 vv = src[idx];
    int row = idx >> 7, col = (idx & 127) * 4;
    *(float4*)&xs[row][col] = vv;
  }
  __syncthreads();
  float acc[16];
  float bz = bias[tid];
  #pragma unroll
  for (int r = 0; r < 16; r++) acc[r] = bz;
  const float4* wrow = (const float4*)(W + (long)tid * 512);
  for (int c = 0; c < 128; c += 2){
    float4 w0 = wrow[c], w1 = wrow[c + 1];
    int e0 = c * 4;
    #pragma unroll
    for (int r = 0; r < 16; r++){
      float4 x0 = *(const float4*)&xs[r][e0];
      float4 x1 = *(const float4*)&xs[r][e0 + 4];
      acc[r] += w0.x*x0.x + w0.y*x0.y + w0.z*x0.z + w0.w*x0.w
              + w1.x*x1.x + w1.y*x1.y + w1.z*x1.z + w1.w*x1.w;
    }
  }
  const float scale = 2.8853900817779268f;  // 2*log2(e): arg pre-scale for exp2-based tanh
  #pragma unroll
  for (int r = 0; r < 16; r++){
    long rr = r0 + r;
    int s = (int)(rr >> 5), b = (int)(rr & 31);      // row = s*32 + b
    outp[((long)(b * Sn + s)) * An + tid] = acc[r] * scale;
  }
}

// ---------------- scores + softmax -> weights[q][k][b] f32 (straight to d_out) ----------------
// block: (qt descending, b). 8 queries/block, 256 threads; thread owns key k = ki*256+tid.
__global__ __launch_bounds__(256) void score_kernel(const float* __restrict__ eat,
                                                    const float* __restrict__ pat,
                                                    const float* __restrict__ vptr,
                                                    float* __restrict__ wout){
  __shared__ float p[8][256];
  __shared__ float v2[256];
  __shared__ float sc[8][1024];
  int tid = threadIdx.x;
  int qt = gridDim.x - 1 - blockIdx.x;   // big-work tiles first
  int b = blockIdx.y;
  #pragma unroll
  for (int q = 0; q < 8; q++){
    int qg = qt * 8 + q;
    int t = qg > 0 ? qg - 1 : 0;
    p[q][tid] = pat[((long)(b * Sn + t)) * An + tid];
  }
  float vv = vptr[tid];
  v2[tid] = 2.0f * vv;
  sc[0][tid] = vv;          // block-local reduction for C = sum(v)
  __syncthreads();
  for (int off = 128; off; off >>= 1){
    if (tid < off) sc[0][tid] += sc[0][tid + off];
    __syncthreads();
  }
  float C = sc[0][0];
  __syncthreads();          // everyone has C before sc is reused for scores
  int Lmax = qt * 8 + 6; if (Lmax < 1) Lmax = 1;   // L of the last query in tile
  for (int ki = 0; ki * 256 < Lmax; ki++){
    int k = ki * 256 + tid;
    if (k < Lmax){
      const float4* ep = (const float4*)(eat + ((long)(b * Sn + k)) * An);
      float acc[8] = {0,0,0,0,0,0,0,0};
      for (int c = 0; c < 32; c++){
        float4 ea = ep[2*c], eb = ep[2*c + 1];
        float e[8] = {ea.x,ea.y,ea.z,ea.w,eb.x,eb.y,eb.z,eb.w};
        const float4* vp = (const float4*)&v2[c * 8];
        float4 va = vp[0], vb = vp[1];
        float vvv[8] = {va.x,va.y,va.z,va.w,vb.x,vb.y,vb.z,vb.w};
        #pragma unroll
        for (int q = 0; q < 8; q++){
          const float4* pp = (const float4*)&p[q][c * 8];
          float4 p0 = pp[0], p1 = pp[1];
          float pq[8] = {p0.x,p0.y,p0.z,p0.w,p1.x,p1.y,p1.z,p1.w};
          #pragma unroll
          for (int j = 0; j < 8; j++){
            // tanh(x) = 1 - 2/(exp(2x)+1); args pre-scaled by 2*log2(e) so exp2 works raw.
            float t = __builtin_amdgcn_exp2f(pq[j] + e[j]);
            acc[q] += vvv[j] * __builtin_amdgcn_rcpf(t + 1.0f);
          }
        }
      }
      #pragma unroll
      for (int q = 0; q < 8; q++){
        int qg = qt * 8 + q;
        int L = qg - 1; if (L < 1) L = 1;
        sc[q][k] = (k < L) ? (C - acc[q]) : -1e30f;
      }
    }
  }
  __syncthreads();
  // softmax: 32-lane group g handles query row g
  int g = tid >> 5, l = tid & 31;
  float m = -1e30f;
  for (int k = l; k < Lmax; k += 32) m = fmaxf(m, sc[g][k]);
  #pragma unroll
  for (int off = 16; off; off >>= 1) m = fmaxf(m, __shfl_xor(m, off, 32));
  const float LOG2E = 1.4426950408889634f;
  float ssum = 0.0f;
  for (int k = l; k < Lmax; k += 32){
    float e = __builtin_amdgcn_exp2f((sc[g][k] - m) * LOG2E);
    sc[g][k] = e; ssum += e;
  }
  #pragma unroll
  for (int off = 16; off; off >>= 1) ssum += __shfl_xor(ssum, off, 32);
  float rl = 1.0f / ssum;
  int qg = qt * 8 + g;
  // weights out: [q][k][b]; k >= Lmax stays zero from memset; k in [L, Lmax) writes exact 0.
  for (int k = l; k < Lmax; k += 32)
    wout[((long)qg * Sn + k) * Bn + b] = sc[g][k] * rl;
}

// ---------------- context[q][b][e] = sum_k w[q][k][b] * emb[k][b][e] ----------------
__global__ __launch_bounds__(256) void context_kernel(const float* __restrict__ w,
                                                      const float* __restrict__ emb,
                                                      float* __restrict__ ctx){
  __shared__ float xl[8][512];
  __shared__ float wl[8][8];
  int tid = threadIdx.x;
  int qt = gridDim.x - 1 - blockIdx.x;
  int b = blockIdx.y;
  int Lmax = qt * 8 + 6; if (Lmax < 1) Lmax = 1;
  int nch = (Lmax + 7) >> 3;
  float acc[8][2];
  #pragma unroll
  for (int q = 0; q < 8; q++){ acc[q][0] = 0.f; acc[q][1] = 0.f; }
  for (int ch = 0; ch < nch; ch++){
    int k0 = ch * 8;
    __syncthreads();
    if (tid < 64){
      int q = tid >> 3, kk = tid & 7;
      // zeros beyond L[q] guaranteed by memset + exact-0 softmax tail
      wl[q][kk] = w[((long)(qt * 8 + q) * Sn + k0 + kk) * Bn + b];
    }
    #pragma unroll
    for (int i = 0; i < 4; i++){
      int idx = i * 256 + tid;           // 0..1023 over 8 rows x 128 float4
      int kr = idx >> 7, col = (idx & 127) * 4;
      const float4* src = (const float4*)(emb + ((long)((k0 + kr) * Bn + b)) * En);
      *(float4*)&xl[kr][col] = src[idx & 127];
    }
    __syncthreads();
    #pragma unroll
    for (int kk = 0; kk < 8; kk++){
      float x0 = xl[kk][tid], x1 = xl[kk][tid + 256];
      #pragma unroll
      for (int q = 0; q < 8; q++){
        float wv = wl[q][kk];
        acc[q][0] += wv * x0;
        acc[q][1] += wv * x1;
      }
    }
  }
  #pragma unroll
  for (int q = 0; q < 8; q++){
    int qg = qt * 8 + q;
    float* dst = ctx + ((long)(qg * Bn + b)) * En;
    dst[tid]       = acc[q][0];
    dst[tid + 256] = acc[q][1];
  }
}

// ---------------- final v2: LDS-tiled fp32 GEMM ----------------
// out[r][h] = outs[r][:].W1[h][:] + ctx[r][:].W2[h][:] + b1[h] + b2[h]
// Old version streamed W rows per-thread (2KB lane stride -> 64 cache lines per
// wave-load; W1+W2 = 2MB >> L1; 4096 blocks x 2MB = 8GB L2 traffic; VALUBusy 21%).
// v2: BM=32 rows x BN=512 cols per block. BN=512 (full width) is REQUIRED: ctx
// aliases outp, so a block must own all columns of its rows (rows block-exclusive,
// no cross-block read-after-write race). BK=8, k-major LDS tiles:
//   - global W reads: per-thread contiguous 32B row chunks (L2-resident, 2GB total)
//   - LDS writes lane-contiguous (conflict-free), compute reads stride-16B b128
//     (conflict-free) + wave-uniform X broadcasts (free)
//   - per k: 8 LDS b128 reads vs 128 FMAs/lane -> FMA-dominated
// 256 thr: rg=tid>>6 -> rows rg*8..+7; ct=tid&63 -> cols ct*4..+3 and 256+ct*4..+3.
__global__ __launch_bounds__(256) void final_kernel(const float* __restrict__ outsp,
                                                    const float* __restrict__ ctx,
                                                    const float* __restrict__ W1,
                                                    const float* __restrict__ b1,
                                                    const float* __restrict__ W2,
                                                    const float* __restrict__ b2,
                                                    float* __restrict__ outp){
  __shared__ float wl1[8][512];
  __shared__ float wl2[8][512];
  __shared__ float xl1[8][32];
  __shared__ float xl2[8][32];
  int tid = threadIdx.x;
  int rg = tid >> 6, ct = tid & 63;
  long r0 = (long)blockIdx.x * 32;

  const float4* w1a = (const float4*)(W1 + (long)tid * 512);
  const float4* w1b = (const float4*)(W1 + (long)(tid + 256) * 512);
  const float4* w2a = (const float4*)(W2 + (long)tid * 512);
  const float4* w2b = (const float4*)(W2 + (long)(tid + 256) * 512);
  // X staging role (threads 0..127 only): 32 rows x 2 float4-groups x 2 matrices
  int xr_ = tid & 31, xg = (tid >> 5) & 1;
  const float* xsrc = ((tid >> 6) & 1) ? ctx : outsp;
  const float* xbase = xsrc + (r0 + xr_) * 512 + xg * 4;
  float (*xl)[32] = ((tid >> 6) & 1) ? xl2 : xl1;

  float acc[8][8];
  #pragma unroll
  for (int r = 0; r < 8; r++)
    #pragma unroll
    for (int j = 0; j < 8; j++) acc[r][j] = 0.f;

  for (int c = 0; c < 64; c++){
    // issue next chunk's global loads before the barrier: overlap with prev compute
    float4 a0 = w1a[2*c], a1 = w1a[2*c+1];
    float4 e0 = w1b[2*c], e1 = w1b[2*c+1];
    float4 f0 = w2a[2*c], f1 = w2a[2*c+1];
    float4 g0 = w2b[2*c], g1 = w2b[2*c+1];
    float4 xv;
    if (tid < 128) xv = *(const float4*)(xbase + c * 8);
    __syncthreads();   // prev chunk's compute done; safe to overwrite tiles
    wl1[0][tid]=a0.x; wl1[1][tid]=a0.y; wl1[2][tid]=a0.z; wl1[3][tid]=a0.w;
    wl1[4][tid]=a1.x; wl1[5][tid]=a1.y; wl1[6][tid]=a1.z; wl1[7][tid]=a1.w;
    wl1[0][tid+256]=e0.x; wl1[1][tid+256]=e0.y; wl1[2][tid+256]=e0.z; wl1[3][tid+256]=e0.w;
    wl1[4][tid+256]=e1.x; wl1[5][tid+256]=e1.y; wl1[6][tid+256]=e1.z; wl1[7][tid+256]=e1.w;
    wl2[0][tid]=f0.x; wl2[1][tid]=f0.y; wl2[2][tid]=f0.z; wl2[3][tid]=f0.w;
    wl2[4][tid]=f1.x; wl2[5][tid]=f1.y; wl2[6][tid]=f1.z; wl2[7][tid]=f1.w;
    wl2[0][tid+256]=g0.x; wl2[1][tid+256]=g0.y; wl2[2][tid+256]=g0.z; wl2[3][tid+256]=g0.w;
    wl2[4][tid+256]=g1.x; wl2[5][tid+256]=g1.y; wl2[6][tid+256]=g1.z; wl2[7][tid+256]=g1.w;
    if (tid < 128){
      xl[xg*4+0][xr_]=xv.x; xl[xg*4+1][xr_]=xv.y; xl[xg*4+2][xr_]=xv.z; xl[xg*4+3][xr_]=xv.w;
    }
    __syncthreads();
    #pragma unroll
    for (int k = 0; k < 8; k++){
      float4 xa = *(const float4*)&xl1[k][rg*8];
      float4 xb = *(const float4*)&xl1[k][rg*8+4];
      float4 ya = *(const float4*)&xl2[k][rg*8];
      float4 yb = *(const float4*)&xl2[k][rg*8+4];
      float4 wa = *(const float4*)&wl1[k][ct*4];
      float4 wb = *(const float4*)&wl1[k][256+ct*4];
      float4 va = *(const float4*)&wl2[k][ct*4];
      float4 vb = *(const float4*)&wl2[k][256+ct*4];
      float xr8[8] = {xa.x,xa.y,xa.z,xa.w,xb.x,xb.y,xb.z,xb.w};
      float yr8[8] = {ya.x,ya.y,ya.z,ya.w,yb.x,yb.y,yb.z,yb.w};
      float wc8[8] = {wa.x,wa.y,wa.z,wa.w,wb.x,wb.y,wb.z,wb.w};
      float vc8[8] = {va.x,va.y,va.z,va.w,vb.x,vb.y,vb.z,vb.w};
      #pragma unroll
      for (int r = 0; r < 8; r++)
        #pragma unroll
        for (int j = 0; j < 8; j++)
          acc[r][j] += xr8[r]*wc8[j] + yr8[r]*vc8[j];
    }
  }

  float bias[8];
  {
    float4 p0 = *(const float4*)(b1 + ct * 4);
    float4 p1 = *(const float4*)(b1 + 256 + ct * 4);
    float4 q0 = *(const float4*)(b2 + ct * 4);
    float4 q1 = *(const float4*)(b2 + 256 + ct * 4);
    bias[0]=p0.x+q0.x; bias[1]=p0.y+q0.y; bias[2]=p0.z+q0.z; bias[3]=p0.w+q0.w;
    bias[4]=p1.x+q1.x; bias[5]=p1.y+q1.y; bias[6]=p1.z+q1.z; bias[7]=p1.w+q1.w;
  }
  // all ctx reads by this block completed before here (staged via LDS with barriers)
  #pragma unroll
  for (int r = 0; r < 8; r++){
    long row = r0 + rg * 8 + r;
    float4 o0, o1;
    o0.x=acc[r][0]+bias[0]; o0.y=acc[r][1]+bias[1]; o0.z=acc[r][2]+bias[2]; o0.w=acc[r][3]+bias[3];
    o1.x=acc[r][4]+bias[4]; o1.y=acc[r][5]+bias[5]; o1.z=acc[r][6]+bias[6]; o1.w=acc[r][7]+bias[7];
    *(float4*)(outp + row * 512 + ct * 4) = o0;
    *(float4*)(outp + row * 512 + 256 + ct * 4) = o1;
  }
}

extern "C" void kernel_launch(void* const* d_in, const int* in_sizes, int n_in,
                              void* d_out, int out_size, void* d_ws, size_t ws_size,
                              hipStream_t stream) {
  const float* outs  = (const float*)d_in[0];
  const float* emb   = (const float*)d_in[1];
  const float* W_enc = (const float*)d_in[2];
  const float* b_enc = (const float*)d_in[3];
  const float* W_dec = (const float*)d_in[4];
  const float* b_dec = (const float*)d_in[5];
  const float* v     = (const float*)d_in[6];
  const float* W_h2h = (const float*)d_in[7];
  const float* b_h2h = (const float*)d_in[8];
  const float* W_e2h = (const float*)d_in[9];
  const float* b_e2h = (const float*)d_in[10];

  float* out0 = (float*)d_out;                        // (S,B,H) = 16,777,216 f32
  float* outw = out0 + (size_t)Sn * Bn * Hn;          // (S,S,B) = 33,554,432 f32

  // NO d_ws usage. Scratch lives inside d_out's out0 region with phase aliasing:
  //   phase 1: eat [b][k][a] at out0[0..8388608), pat [b][s][a] at out0[8388608..16777216)
  //   phase 2 (after score): ctx [q*B+b][E] at out0[0..16777216)
  //   phase 3: final output overwrites out0 (row-exclusive blocks, staged reads, no race)
  float* eat = out0;
  float* pat = out0 + (size_t)8388608;
  float* ctx = out0;

  hipMemsetAsync(outw, 0, (size_t)Sn * Sn * Bn * 4, stream);   // zero masked weights
  proj_kernel<<<2048, 256, 0, stream>>>(emb,  W_enc, b_enc, eat);
  proj_kernel<<<2048, 256, 0, stream>>>(outs, W_dec, b_dec, pat);
  score_kernel<<<dim3(128, 32), 256, 0, stream>>>(eat, pat, v, outw);
  context_kernel<<<dim3(128, 32), 256, 0, stream>>>(outw, emb, ctx);
  final_kernel<<<1024, 256, 0, stream>>>(outs, ctx, W_h2h, b_h2h, W_e2h, b_e2h, out0);
}

// Round 2
// 2751.562 us; speedup vs baseline: 1.5380x; 1.1488x over previous
//
#include <hip/hip_runtime.h>

// S=1024 seq, B=32 batch, H=512 hid, E=512 emb, A=256 att — ALL f32 per reference
#define Sn 1024
#define Bn 32
#define Hn 512
#define En 512
#define An 256

// ---------------- projection: out[b][s][a] = exp2( scale*(X[s*B+b][:] . W[a][:] + bias[a]) )
// X: [S*B][512] f32, W: [256][512] f32. 16 rows/block, 256 threads (col=a=tid).
// NOTE: stores the EXPONENTIAL of the scaled projection. score_kernel uses
// exp2(p+e) = exp2(p)*exp2(e), hoisting the quarter-rate exp2 out of the O(S^2*B*A)
// inner loop into this O(S*B*A) epilogue. |scale*proj| <~ 8 so exp2 is in [2^-8,2^8].
__global__ __launch_bounds__(256) void proj_kernel(const float* __restrict__ X,
                                                   const float* __restrict__ W,
                                                   const float* __restrict__ bias,
                                                   float* __restrict__ outp){
  __shared__ float xs[16][512];
  int tid = threadIdx.x;
  long r0 = (long)blockIdx.x * 16;
  const float4* src = (const float4*)(X + r0 * 512);   // 16 rows = 2048 float4
  #pragma unroll
  for (int i = 0; i < 8; i++){
    int idx = i * 256 + tid;
    float4 vv = src[idx];
    int row = idx >> 7, col = (idx & 127) * 4;
    *(float4*)&xs[row][col] = vv;
  }
  __syncthreads();
  float acc[16];
  float bz = bias[tid];
  #pragma unroll
  for (int r = 0; r < 16; r++) acc[r] = bz;
  const float4* wrow = (const float4*)(W + (long)tid * 512);
  for (int c = 0; c < 128; c += 2){
    float4 w0 = wrow[c], w1 = wrow[c + 1];
    int e0 = c * 4;
    #pragma unroll
    for (int r = 0; r < 16; r++){
      float4 x0 = *(const float4*)&xs[r][e0];
      float4 x1 = *(const float4*)&xs[r][e0 + 4];
      acc[r] += w0.x*x0.x + w0.y*x0.y + w0.z*x0.z + w0.w*x0.w
              + w1.x*x1.x + w1.y*x1.y + w1.z*x1.z + w1.w*x1.w;
    }
  }
  const float scale = 2.8853900817779268f;  // 2*log2(e): arg pre-scale for exp2-based tanh
  #pragma unroll
  for (int r = 0; r < 16; r++){
    long rr = r0 + r;
    int s = (int)(rr >> 5), b = (int)(rr & 31);      // row = s*32 + b
    outp[((long)(b * Sn + s)) * An + tid] = __builtin_amdgcn_exp2f(acc[r] * scale);
  }
}

// ---------------- scores + softmax -> weights[q][k][b] f32 (straight to d_out) ----------------
// block: (qt descending, b). 8 queries/block, 256 threads; thread owns key k = ki*256+tid.
// eat/pat now hold E=exp2(e'), P=exp2(p'). tanh(x)=1-2/(exp(2x)+1) ->
// score = C - sum_a 2*v_a / (P_a*E_a + 1). Inner loop: fma + rcp + fma (12 cyc/elem
// vs 20 with in-loop exp2).
__global__ __launch_bounds__(256) void score_kernel(const float* __restrict__ eat,
                                                    const float* __restrict__ pat,
                                                    const float* __restrict__ vptr,
                                                    float* __restrict__ wout){
  __shared__ float p[8][256];
  __shared__ float v2[256];
  __shared__ float sc[8][1024];
  int tid = threadIdx.x;
  int qt = gridDim.x - 1 - blockIdx.x;   // big-work tiles first
  int b = blockIdx.y;
  #pragma unroll
  for (int q = 0; q < 8; q++){
    int qg = qt * 8 + q;
    int t = qg > 0 ? qg - 1 : 0;
    p[q][tid] = pat[((long)(b * Sn + t)) * An + tid];   // P = exp2(p')
  }
  float vv = vptr[tid];
  v2[tid] = 2.0f * vv;
  sc[0][tid] = vv;          // block-local reduction for C = sum(v)
  __syncthreads();
  for (int off = 128; off; off >>= 1){
    if (tid < off) sc[0][tid] += sc[0][tid + off];
    __syncthreads();
  }
  float C = sc[0][0];
  __syncthreads();          // everyone has C before sc is reused for scores
  int Lmax = qt * 8 + 6; if (Lmax < 1) Lmax = 1;   // L of the last query in tile
  for (int ki = 0; ki * 256 < Lmax; ki++){
    int k = ki * 256 + tid;
    if (k < Lmax){
      const float4* ep = (const float4*)(eat + ((long)(b * Sn + k)) * An);
      float acc[8] = {0,0,0,0,0,0,0,0};
      for (int c = 0; c < 32; c++){
        float4 ea = ep[2*c], eb = ep[2*c + 1];          // E = exp2(e')
        float e8[8] = {ea.x,ea.y,ea.z,ea.w,eb.x,eb.y,eb.z,eb.w};
        const float4* vp = (const float4*)&v2[c * 8];
        float4 va = vp[0], vb = vp[1];
        float vv8[8] = {va.x,va.y,va.z,va.w,vb.x,vb.y,vb.z,vb.w};
        #pragma unroll
        for (int q = 0; q < 8; q++){
          const float4* pp = (const float4*)&p[q][c * 8];
          float4 p0 = pp[0], p1 = pp[1];
          float pq8[8] = {p0.x,p0.y,p0.z,p0.w,p1.x,p1.y,p1.z,p1.w};
          #pragma unroll
          for (int j = 0; j < 8; j++){
            float t = __builtin_fmaf(pq8[j], e8[j], 1.0f);   // 1 + P*E
            acc[q] += vv8[j] * __builtin_amdgcn_rcpf(t);
          }
        }
      }
      #pragma unroll
      for (int q = 0; q < 8; q++){
        int qg = qt * 8 + q;
        int L = qg - 1; if (L < 1) L = 1;
        sc[q][k] = (k < L) ? (C - acc[q]) : -1e30f;
      }
    }
  }
  __syncthreads();
  // softmax: 32-lane group g handles query row g
  int g = tid >> 5, l = tid & 31;
  float m = -1e30f;
  for (int k = l; k < Lmax; k += 32) m = fmaxf(m, sc[g][k]);
  #pragma unroll
  for (int off = 16; off; off >>= 1) m = fmaxf(m, __shfl_xor(m, off, 32));
  const float LOG2E = 1.4426950408889634f;
  float ssum = 0.0f;
  for (int k = l; k < Lmax; k += 32){
    float e = __builtin_amdgcn_exp2f((sc[g][k] - m) * LOG2E);
    sc[g][k] = e; ssum += e;
  }
  #pragma unroll
  for (int off = 16; off; off >>= 1) ssum += __shfl_xor(ssum, off, 32);
  float rl = 1.0f / ssum;
  int qg = qt * 8 + g;
  // weights out: [q][k][b]; k >= Lmax stays zero from memset; k in [L, Lmax) writes exact 0.
  for (int k = l; k < Lmax; k += 32)
    wout[((long)qg * Sn + k) * Bn + b] = sc[g][k] * rl;
}

// ---------------- context[q][b][e] = sum_k w[q][k][b] * emb[k][b][e] ----------------
__global__ __launch_bounds__(256) void context_kernel(const float* __restrict__ w,
                                                      const float* __restrict__ emb,
                                                      float* __restrict__ ctx){
  __shared__ float xl[8][512];
  __shared__ float wl[8][8];
  int tid = threadIdx.x;
  int qt = gridDim.x - 1 - blockIdx.x;
  int b = blockIdx.y;
  int Lmax = qt * 8 + 6; if (Lmax < 1) Lmax = 1;
  int nch = (Lmax + 7) >> 3;
  float acc[8][2];
  #pragma unroll
  for (int q = 0; q < 8; q++){ acc[q][0] = 0.f; acc[q][1] = 0.f; }
  for (int ch = 0; ch < nch; ch++){
    int k0 = ch * 8;
    __syncthreads();
    if (tid < 64){
      int q = tid >> 3, kk = tid & 7;
      // zeros beyond L[q] guaranteed by memset + exact-0 softmax tail
      wl[q][kk] = w[((long)(qt * 8 + q) * Sn + k0 + kk) * Bn + b];
    }
    #pragma unroll
    for (int i = 0; i < 4; i++){
      int idx = i * 256 + tid;           // 0..1023 over 8 rows x 128 float4
      int kr = idx >> 7, col = (idx & 127) * 4;
      const float4* src = (const float4*)(emb + ((long)((k0 + kr) * Bn + b)) * En);
      *(float4*)&xl[kr][col] = src[idx & 127];
    }
    __syncthreads();
    #pragma unroll
    for (int kk = 0; kk < 8; kk++){
      float x0 = xl[kk][tid], x1 = xl[kk][tid + 256];
      #pragma unroll
      for (int q = 0; q < 8; q++){
        float wv = wl[q][kk];
        acc[q][0] += wv * x0;
        acc[q][1] += wv * x1;
      }
    }
  }
  #pragma unroll
  for (int q = 0; q < 8; q++){
    int qg = qt * 8 + q;
    float* dst = ctx + ((long)(qg * Bn + b)) * En;
    dst[tid]       = acc[q][0];
    dst[tid + 256] = acc[q][1];
  }
}

// ---------------- final v2: LDS-tiled fp32 GEMM ----------------
// out[r][h] = outs[r][:].W1[h][:] + ctx[r][:].W2[h][:] + b1[h] + b2[h]
// BM=32 rows x BN=512 cols per block. BN=512 (full width) is REQUIRED: ctx
// aliases outp, so a block must own all columns of its rows (rows block-exclusive,
// no cross-block read-after-write race). BK=8, k-major LDS tiles.
__global__ __launch_bounds__(256) void final_kernel(const float* __restrict__ outsp,
                                                    const float* __restrict__ ctx,
                                                    const float* __restrict__ W1,
                                                    const float* __restrict__ b1,
                                                    const float* __restrict__ W2,
                                                    const float* __restrict__ b2,
                                                    float* __restrict__ outp){
  __shared__ float wl1[8][512];
  __shared__ float wl2[8][512];
  __shared__ float xl1[8][32];
  __shared__ float xl2[8][32];
  int tid = threadIdx.x;
  int rg = tid >> 6, ct = tid & 63;
  long r0 = (long)blockIdx.x * 32;

  const float4* w1a = (const float4*)(W1 + (long)tid * 512);
  const float4* w1b = (const float4*)(W1 + (long)(tid + 256) * 512);
  const float4* w2a = (const float4*)(W2 + (long)tid * 512);
  const float4* w2b = (const float4*)(W2 + (long)(tid + 256) * 512);
  // X staging role (threads 0..127 only): 32 rows x 2 float4-groups x 2 matrices
  int xr_ = tid & 31, xg = (tid >> 5) & 1;
  const float* xsrc = ((tid >> 6) & 1) ? ctx : outsp;
  const float* xbase = xsrc + (r0 + xr_) * 512 + xg * 4;
  float (*xl)[32] = ((tid >> 6) & 1) ? xl2 : xl1;

  float acc[8][8];
  #pragma unroll
  for (int r = 0; r < 8; r++)
    #pragma unroll
    for (int j = 0; j < 8; j++) acc[r][j] = 0.f;

  for (int c = 0; c < 64; c++){
    // issue next chunk's global loads before the barrier: overlap with prev compute
    float4 a0 = w1a[2*c], a1 = w1a[2*c+1];
    float4 e0 = w1b[2*c], e1 = w1b[2*c+1];
    float4 f0 = w2a[2*c], f1 = w2a[2*c+1];
    float4 g0 = w2b[2*c], g1 = w2b[2*c+1];
    float4 xv;
    if (tid < 128) xv = *(const float4*)(xbase + c * 8);
    __syncthreads();   // prev chunk's compute done; safe to overwrite tiles
    wl1[0][tid]=a0.x; wl1[1][tid]=a0.y; wl1[2][tid]=a0.z; wl1[3][tid]=a0.w;
    wl1[4][tid]=a1.x; wl1[5][tid]=a1.y; wl1[6][tid]=a1.z; wl1[7][tid]=a1.w;
    wl1[0][tid+256]=e0.x; wl1[1][tid+256]=e0.y; wl1[2][tid+256]=e0.z; wl1[3][tid+256]=e0.w;
    wl1[4][tid+256]=e1.x; wl1[5][tid+256]=e1.y; wl1[6][tid+256]=e1.z; wl1[7][tid+256]=e1.w;
    wl2[0][tid]=f0.x; wl2[1][tid]=f0.y; wl2[2][tid]=f0.z; wl2[3][tid]=f0.w;
    wl2[4][tid]=f1.x; wl2[5][tid]=f1.y; wl2[6][tid]=f1.z; wl2[7][tid]=f1.w;
    wl2[0][tid+256]=g0.x; wl2[1][tid+256]=g0.y; wl2[2][tid+256]=g0.z; wl2[3][tid+256]=g0.w;
    wl2[4][tid+256]=g1.x; wl2[5][tid+256]=g1.y; wl2[6][tid+256]=g1.z; wl2[7][tid+256]=g1.w;
    if (tid < 128){
      xl[xg*4+0][xr_]=xv.x; xl[xg*4+1][xr_]=xv.y; xl[xg*4+2][xr_]=xv.z; xl[xg*4+3][xr_]=xv.w;
    }
    __syncthreads();
    #pragma unroll
    for (int k = 0; k < 8; k++){
      float4 xa = *(const float4*)&xl1[k][rg*8];
      float4 xb = *(const float4*)&xl1[k][rg*8+4];
      float4 ya = *(const float4*)&xl2[k][rg*8];
      float4 yb = *(const float4*)&xl2[k][rg*8+4];
      float4 wa = *(const float4*)&wl1[k][ct*4];
      float4 wb = *(const float4*)&wl1[k][256+ct*4];
      float4 va = *(const float4*)&wl2[k][ct*4];
      float4 vb = *(const float4*)&wl2[k][256+ct*4];
      float xr8[8] = {xa.x,xa.y,xa.z,xa.w,xb.x,xb.y,xb.z,xb.w};
      float yr8[8] = {ya.x,ya.y,ya.z,ya.w,yb.x,yb.y,yb.z,yb.w};
      float wc8[8] = {wa.x,wa.y,wa.z,wa.w,wb.x,wb.y,wb.z,wb.w};
      float vc8[8] = {va.x,va.y,va.z,va.w,vb.x,vb.y,vb.z,vb.w};
      #pragma unroll
      for (int r = 0; r < 8; r++)
        #pragma unroll
        for (int j = 0; j < 8; j++)
          acc[r][j] += xr8[r]*wc8[j] + yr8[r]*vc8[j];
    }
  }

  float bias[8];
  {
    float4 p0 = *(const float4*)(b1 + ct * 4);
    float4 p1 = *(const float4*)(b1 + 256 + ct * 4);
    float4 q0 = *(const float4*)(b2 + ct * 4);
    float4 q1 = *(const float4*)(b2 + 256 + ct * 4);
    bias[0]=p0.x+q0.x; bias[1]=p0.y+q0.y; bias[2]=p0.z+q0.z; bias[3]=p0.w+q0.w;
    bias[4]=p1.x+q1.x; bias[5]=p1.y+q1.y; bias[6]=p1.z+q1.z; bias[7]=p1.w+q1.w;
  }
  // all ctx reads by this block completed before here (staged via LDS with barriers)
  #pragma unroll
  for (int r = 0; r < 8; r++){
    long row = r0 + rg * 8 + r;
    float4 o0, o1;
    o0.x=acc[r][0]+bias[0]; o0.y=acc[r][1]+bias[1]; o0.z=acc[r][2]+bias[2]; o0.w=acc[r][3]+bias[3];
    o1.x=acc[r][4]+bias[4]; o1.y=acc[r][5]+bias[5]; o1.z=acc[r][6]+bias[6]; o1.w=acc[r][7]+bias[7];
    *(float4*)(outp + row * 512 + ct * 4) = o0;
    *(float4*)(outp + row * 512 + 256 + ct * 4) = o1;
  }
}

extern "C" void kernel_launch(void* const* d_in, const int* in_sizes, int n_in,
                              void* d_out, int out_size, void* d_ws, size_t ws_size,
                              hipStream_t stream) {
  const float* outs  = (const float*)d_in[0];
  const float* emb   = (const float*)d_in[1];
  const float* W_enc = (const float*)d_in[2];
  const float* b_enc = (const float*)d_in[3];
  const float* W_dec = (const float*)d_in[4];
  const float* b_dec = (const float*)d_in[5];
  const float* v     = (const float*)d_in[6];
  const float* W_h2h = (const float*)d_in[7];
  const float* b_h2h = (const float*)d_in[8];
  const float* W_e2h = (const float*)d_in[9];
  const float* b_e2h = (const float*)d_in[10];

  float* out0 = (float*)d_out;                        // (S,B,H) = 16,777,216 f32
  float* outw = out0 + (size_t)Sn * Bn * Hn;          // (S,S,B) = 33,554,432 f32

  // NO d_ws usage. Scratch lives inside d_out's out0 region with phase aliasing:
  //   phase 1: eat [b][k][a] at out0[0..8388608), pat [b][s][a] at out0[8388608..16777216)
  //            (both hold exp2 of the scaled projection)
  //   phase 2 (after score): ctx [q*B+b][E] at out0[0..16777216)
  //   phase 3: final output overwrites out0 (row-exclusive blocks, staged reads, no race)
  float* eat = out0;
  float* pat = out0 + (size_t)8388608;
  float* ctx = out0;

  hipMemsetAsync(outw, 0, (size_t)Sn * Sn * Bn * 4, stream);   // zero masked weights
  proj_kernel<<<2048, 256, 0, stream>>>(emb,  W_enc, b_enc, eat);
  proj_kernel<<<2048, 256, 0, stream>>>(outs, W_dec, b_dec, pat);
  score_kernel<<<dim3(128, 32), 256, 0, stream>>>(eat, pat, v, outw);
  context_kernel<<<dim3(128, 32), 256, 0, stream>>>(outw, emb, ctx);
  final_kernel<<<1024, 256, 0, stream>>>(outs, ctx, W_h2h, b_h2h, W_e2h, b_e2h, out0);
}